// Round 1
// baseline (2166.558 us; speedup 1.0000x reference)
//
#include <hip/hip_runtime.h>

// Problem constants (from reference setup_inputs)
#define NNODES 50000
#define FT 8        // feature_type_count
#define DD 64       // D
#define KK 16384    // K

// Atomic float max via integer atomics (works for mixed signs):
// nonneg floats: int bits are monotone increasing -> atomicMax on int
// negative floats: uint bits are monotone DEcreasing -> atomicMin on uint
// Sentinel 0xFFFFFFFF (= -NaN bits): int -1 loses to any nonneg int-max;
// uint max value loses to any negative's uint-min. So memset(0xFF) == -inf init.
__device__ __forceinline__ void atomicMaxF(float* addr, float v) {
    int vi = __float_as_int(v);
    if (vi >= 0) {
        atomicMax((int*)addr, vi);
    } else {
        atomicMin((unsigned int*)addr, (unsigned int)vi);
    }
}

__global__ void edge_kernel(const int* __restrict__ esrc,
                            const int* __restrict__ edst,
                            const int* __restrict__ rawd,
                            const float4* __restrict__ evals,
                            float* __restrict__ acc,
                            int* __restrict__ cnt,
                            int nE) {
    long long t = (long long)blockIdx.x * blockDim.x + threadIdx.x;
    int e = (int)(t >> 4);
    if (e >= nE) return;
    int c = (int)(t & 15);          // which float4 chunk of the 64-dim row
    int src = esrc[e];
    int typ = rawd[edst[e]];
    if (c == 0) atomicAdd(cnt + src * FT + typ, 1);
    float4 v = evals[(long long)e * 16 + c];   // coalesced: lane i reads chunk i
    float* base = acc + (((long long)src * FT + typ) * DD) + c * 4;
    atomicMaxF(base + 0, v.x);
    atomicMaxF(base + 1, v.y);
    atomicMaxF(base + 2, v.z);
    atomicMaxF(base + 3, v.w);
}

__global__ void gather_kernel(const int* __restrict__ core,
                              const float* __restrict__ acc,
                              const int* __restrict__ cnt,
                              float* __restrict__ out) {
    int t = blockIdx.x * blockDim.x + threadIdx.x;
    if (t >= KK * FT * 16) return;
    int d4 = t & 15;
    int f = (t >> 4) & 7;
    int k = t >> 7;
    int node = core[k];
    const int* cb = cnt + node * FT;
    int matched = cb[f];
    int deg = 0;
#pragma unroll
    for (int j = 0; j < FT; ++j) deg += cb[j];
    float4 r;
    if (matched == 0) {
        // no matching edges: either no edges at all (-inf -> 0) or all masked-to-zero
        r = make_float4(0.f, 0.f, 0.f, 0.f);
    } else {
        float4 m = *(const float4*)(acc + ((long long)node * FT + f) * DD + d4 * 4);
        if (matched < deg) {
            // at least one non-matching edge contributes a 0 vector to the max
            r.x = fmaxf(m.x, 0.f);
            r.y = fmaxf(m.y, 0.f);
            r.z = fmaxf(m.z, 0.f);
            r.w = fmaxf(m.w, 0.f);
        } else {
            // every edge of this node matches type f: plain max (can be negative)
            r = m;
        }
    }
    *(float4*)(out + ((long long)k * FT + f) * DD + d4 * 4) = r;
}

extern "C" void kernel_launch(void* const* d_in, const int* in_sizes, int n_in,
                              void* d_out, int out_size, void* d_ws, size_t ws_size,
                              hipStream_t stream) {
    const int*   rawd  = (const int*)d_in[0];
    const int*   esrc  = (const int*)d_in[1];
    const int*   edst  = (const int*)d_in[2];
    const float* evals = (const float*)d_in[3];
    const int*   core  = (const int*)d_in[4];
    int nE = in_sizes[1];

    float* acc = (float*)d_ws;
    size_t accBytes = (size_t)NNODES * FT * DD * sizeof(float);   // 102.4 MB
    int* cnt = (int*)((char*)d_ws + accBytes);                    // +1.6 MB

    hipMemsetAsync(acc, 0xFF, accBytes, stream);                  // -inf sentinel
    hipMemsetAsync(cnt, 0, (size_t)NNODES * FT * sizeof(int), stream);

    long long threadsE = (long long)nE * 16;
    edge_kernel<<<(int)((threadsE + 255) / 256), 256, 0, stream>>>(
        esrc, edst, rawd, (const float4*)evals, acc, cnt, nE);

    int threadsG = KK * FT * 16;
    gather_kernel<<<(threadsG + 255) / 256, 256, 0, stream>>>(
        core, acc, cnt, (float*)d_out);
}

// Round 2
// 163.992 us; speedup vs baseline: 13.2113x; 13.2113x over previous
//
#include <hip/hip_runtime.h>

#define NNODES 50000
#define FT 8
#define DD 64
#define KK 16384

// ---------------- ws layout (int units) ----------------
// cnt    [0,       50000)
// needed [50000,  100000)
// gtot   [100000, 100002)
// offs   [100002, 150002)
// cursor [150002, 200002)
// remap  [200002, 250002)
// sorted [250004, 250004+nE)           (packed (e<<3)|typ, needed edges only)
// accc   floats @ byte 7400016          (16384 slots x 512 floats, 16B aligned)

__global__ void mark_kernel(const int* __restrict__ core, int* __restrict__ needed) {
    int k = blockIdx.x * 256 + threadIdx.x;
    if (k < KK) needed[core[k]] = 1;
}

__global__ void hist_kernel(const int* __restrict__ esrc, const int* __restrict__ needed,
                            int* __restrict__ cnt, int nE) {
    int e = blockIdx.x * 256 + threadIdx.x;
    if (e >= nE) return;
    int s = esrc[e];
    if (needed[s]) atomicAdd(&cnt[s], 1);
}

// Wave-aggregated bump allocator: contiguous edge range per needed node
// (offs/cursor) and a compact output slot per needed node (remap).
__global__ void alloc_kernel(const int* __restrict__ cnt, const int* __restrict__ needed,
                             int* __restrict__ offs, int* __restrict__ cursor,
                             int* __restrict__ remap, int* __restrict__ gtot) {
    int i = blockIdx.x * 256 + threadIdx.x;
    int lane = threadIdx.x & 63;
    int nd = (i < NNODES) ? needed[i] : 0;
    int v  = nd ? cnt[i] : 0;   // edges to allocate
    int s1 = nd;                // slots to allocate
    int sc = v, ss = s1;        // inclusive wave scans
#pragma unroll
    for (int o = 1; o < 64; o <<= 1) {
        int t0 = __shfl_up(sc, o), t1 = __shfl_up(ss, o);
        if (lane >= o) { sc += t0; ss += t1; }
    }
    int tot0 = __shfl(sc, 63), tot1 = __shfl(ss, 63);
    int b0 = 0, b1 = 0;
    if (lane == 63) { b0 = atomicAdd(&gtot[0], tot0); b1 = atomicAdd(&gtot[1], tot1); }
    b0 = __shfl(b0, 63); b1 = __shfl(b1, 63);
    if (i < NNODES) {
        int st = b0 + sc - v;       // exclusive within wave + global base
        offs[i] = st; cursor[i] = st;
        remap[i] = b1 + ss - s1;
    }
}

__global__ void scatter_kernel(const int* __restrict__ esrc, const int* __restrict__ edst,
                               const int* __restrict__ rawd, const int* __restrict__ needed,
                               int* __restrict__ cursor, int* __restrict__ sorted, int nE) {
    int e = blockIdx.x * 256 + threadIdx.x;
    if (e >= nE) return;
    int s = esrc[e];
    if (!needed[s]) return;
    int typ = rawd[edst[e]];
    int pos = atomicAdd(&cursor[s], 1);
    sorted[pos] = (e << 3) | typ;
}

// One wave per node (lane = dim). Register max per feature type, zero atomics.
__global__ void compute_kernel(const int* __restrict__ offs, const int* __restrict__ cnt,
                               const int* __restrict__ sorted, const int* __restrict__ needed,
                               const int* __restrict__ remap, const float* __restrict__ evals,
                               float* __restrict__ accc) {
    int wave = (blockIdx.x * blockDim.x + threadIdx.x) >> 6;
    int lane = threadIdx.x & 63;
    if (wave >= NNODES) return;
    if (!needed[wave]) return;
    int start = offs[wave];
    int deg   = cnt[wave];
    int end   = start + deg;

    float r[FT];
    int   c[FT];
#pragma unroll
    for (int t = 0; t < FT; ++t) { r[t] = -INFINITY; c[t] = 0; }

    int i = start;
    for (; i + 1 < end; i += 2) {       // 2-edge unroll for load overlap
        int pk0 = sorted[i], pk1 = sorted[i + 1];
        int t0 = pk0 & 7, t1 = pk1 & 7;
        float v0 = evals[(pk0 >> 3) * DD + lane];
        float v1 = evals[(pk1 >> 3) * DD + lane];
#pragma unroll
        for (int t = 0; t < FT; ++t) {
            bool m0 = (t0 == t); r[t] = m0 ? fmaxf(r[t], v0) : r[t]; c[t] += m0;
            bool m1 = (t1 == t); r[t] = m1 ? fmaxf(r[t], v1) : r[t]; c[t] += m1;
        }
    }
    if (i < end) {
        int pk = sorted[i];
        int tt = pk & 7;
        float v = evals[(pk >> 3) * DD + lane];
#pragma unroll
        for (int t = 0; t < FT; ++t) {
            bool m = (tt == t); r[t] = m ? fmaxf(r[t], v) : r[t]; c[t] += m;
        }
    }

    int slot = remap[wave];
    float* outp = accc + slot * (FT * DD) + lane;
#pragma unroll
    for (int f = 0; f < FT; ++f) {
        int matched = c[f];
        float val;
        if (matched == 0)        val = 0.0f;               // no matching edges -> 0
        else if (matched < deg)  val = fmaxf(r[f], 0.0f);  // a masked-to-zero edge exists
        else                     val = r[f];               // every edge matched this type
        outp[f * DD] = val;
    }
}

__global__ void gather_kernel(const int* __restrict__ core, const int* __restrict__ remap,
                              const float4* __restrict__ acc4, float4* __restrict__ out4) {
    int t = blockIdx.x * 256 + threadIdx.x;
    if (t >= KK * 128) return;      // 512 floats = 128 float4 per row
    int x = t & 127;
    int k = t >> 7;
    int slot = remap[core[k]];
    out4[t] = acc4[slot * 128 + x];
}

extern "C" void kernel_launch(void* const* d_in, const int* in_sizes, int n_in,
                              void* d_out, int out_size, void* d_ws, size_t ws_size,
                              hipStream_t stream) {
    const int*   rawd  = (const int*)d_in[0];
    const int*   esrc  = (const int*)d_in[1];
    const int*   edst  = (const int*)d_in[2];
    const float* evals = (const float*)d_in[3];
    const int*   core  = (const int*)d_in[4];
    int nE = in_sizes[1];

    int* wsi    = (int*)d_ws;
    int* cnt    = wsi;
    int* needed = wsi + 50000;
    int* gtot   = wsi + 100000;
    int* offs   = wsi + 100002;
    int* cursor = wsi + 150002;
    int* remap  = wsi + 200002;
    int* sorted = wsi + 250004;
    float* accc = (float*)((char*)d_ws + 7400016);   // 16B aligned

    // zero cnt + needed + gtot in one contiguous memset
    hipMemsetAsync(cnt, 0, (size_t)100002 * sizeof(int), stream);

    mark_kernel<<<(KK + 255) / 256, 256, 0, stream>>>(core, needed);
    hist_kernel<<<(nE + 255) / 256, 256, 0, stream>>>(esrc, needed, cnt, nE);
    alloc_kernel<<<(NNODES + 255) / 256, 256, 0, stream>>>(cnt, needed, offs, cursor, remap, gtot);
    scatter_kernel<<<(nE + 255) / 256, 256, 0, stream>>>(esrc, edst, rawd, needed, cursor, sorted, nE);

    long long cthreads = (long long)NNODES * 64;
    compute_kernel<<<(int)((cthreads + 255) / 256), 256, 0, stream>>>(
        offs, cnt, sorted, needed, remap, evals, accc);

    int gthreads = KK * 128;
    gather_kernel<<<(gthreads + 255) / 256, 256, 0, stream>>>(
        core, remap, (const float4*)accc, (float4*)d_out);
}

// Round 3
// 126.825 us; speedup vs baseline: 17.0830x; 1.2931x over previous
//
#include <hip/hip_runtime.h>

#define NNODES 50000
#define FT 8
#define DD 64
#define KK 16384

// ---------------- ws layout (int units) ----------------
// cnt       [0,      50000)   true degree of each node (needed nodes only)
// needed    [50000, 100000)
// gtot      [100000,100002)   [0]=edge-slab cursor, [1]=slot cursor
// head      [100004,150004)   node -> first k (linked list), -1 = none
// nxt       [150004,166388)   k -> next k
// slot_node [166388,182772)   compact slot -> node
// slot_off  [182772,199156)   compact slot -> start offset in sorted
// cursor    [199156,249156)   per-node bump cursor for scatter
// sorted    [249156,249156+nE) packed (e<<3)|typ for needed edges

__global__ void init_kernel(int* __restrict__ cnt, int* __restrict__ needed,
                            int* __restrict__ head, int* __restrict__ gtot) {
    int i = blockIdx.x * 256 + threadIdx.x;
    if (i < NNODES) { cnt[i] = 0; needed[i] = 0; head[i] = -1; }
    if (i < 2) gtot[i] = 0;
}

__global__ void mark_kernel(const int* __restrict__ core, int* __restrict__ needed,
                            int* __restrict__ head, int* __restrict__ nxt) {
    int k = blockIdx.x * 256 + threadIdx.x;
    if (k >= KK) return;
    int node = core[k];
    needed[node] = 1;
    nxt[k] = atomicExch(&head[node], k);   // push k onto node's list
}

__global__ void hist_kernel(const int4* __restrict__ esrc4, const int* __restrict__ needed,
                            int* __restrict__ cnt, int nE) {
    int t = blockIdx.x * 256 + threadIdx.x;
    int e = t * 4;
    if (e >= nE) return;
    if (e + 3 < nE) {
        int4 s = esrc4[t];
        if (needed[s.x]) atomicAdd(&cnt[s.x], 1);
        if (needed[s.y]) atomicAdd(&cnt[s.y], 1);
        if (needed[s.z]) atomicAdd(&cnt[s.z], 1);
        if (needed[s.w]) atomicAdd(&cnt[s.w], 1);
    } else {
        const int* esrc = (const int*)esrc4;
        for (; e < nE; ++e) { int s = esrc[e]; if (needed[s]) atomicAdd(&cnt[s], 1); }
    }
}

// Wave-aggregated bump allocation of edge ranges + compact slots (needed nodes).
__global__ void alloc_kernel(const int* __restrict__ cnt, const int* __restrict__ needed,
                             int* __restrict__ cursor, int* __restrict__ slot_node,
                             int* __restrict__ slot_off, int* __restrict__ gtot) {
    int i = blockIdx.x * 256 + threadIdx.x;
    int lane = threadIdx.x & 63;
    int nd = (i < NNODES) ? needed[i] : 0;
    int v  = nd ? cnt[i] : 0;
    int sc = v, ss = nd;
#pragma unroll
    for (int o = 1; o < 64; o <<= 1) {
        int t0 = __shfl_up(sc, o), t1 = __shfl_up(ss, o);
        if (lane >= o) { sc += t0; ss += t1; }
    }
    int tot0 = __shfl(sc, 63), tot1 = __shfl(ss, 63);
    int b0 = 0, b1 = 0;
    if (lane == 63) { b0 = atomicAdd(&gtot[0], tot0); b1 = atomicAdd(&gtot[1], tot1); }
    b0 = __shfl(b0, 63); b1 = __shfl(b1, 63);
    if (nd) {
        int st = b0 + sc - v;
        int sl = b1 + ss - 1;
        cursor[i] = st;
        slot_node[sl] = i;
        slot_off[sl]  = st;
    }
}

__global__ void scatter_kernel(const int4* __restrict__ esrc4, const int4* __restrict__ edst4,
                               const int* __restrict__ rawd, const int* __restrict__ needed,
                               int* __restrict__ cursor, int* __restrict__ sorted, int nE) {
    int t = blockIdx.x * 256 + threadIdx.x;
    int e = t * 4;
    if (e >= nE) return;
    if (e + 3 < nE) {
        int4 s = esrc4[t];
        int4 d = edst4[t];
        if (needed[s.x]) { int p = atomicAdd(&cursor[s.x], 1); sorted[p] = ((e    ) << 3) | rawd[d.x]; }
        if (needed[s.y]) { int p = atomicAdd(&cursor[s.y], 1); sorted[p] = ((e + 1) << 3) | rawd[d.y]; }
        if (needed[s.z]) { int p = atomicAdd(&cursor[s.z], 1); sorted[p] = ((e + 2) << 3) | rawd[d.z]; }
        if (needed[s.w]) { int p = atomicAdd(&cursor[s.w], 1); sorted[p] = ((e + 3) << 3) | rawd[d.w]; }
    } else {
        const int* esrc = (const int*)esrc4;
        const int* edst = (const int*)edst4;
        for (; e < nE; ++e) {
            int s = esrc[e];
            if (needed[s]) { int p = atomicAdd(&cursor[s], 1); sorted[p] = (e << 3) | rawd[edst[e]]; }
        }
    }
}

// One wave per compact slot (lane = dim). Register max per type, direct out write.
__global__ void compute_kernel(const int* __restrict__ slot_node, const int* __restrict__ slot_off,
                               const int* __restrict__ cnt, const int* __restrict__ sorted,
                               const int* __restrict__ head, const int* __restrict__ nxt,
                               const float* __restrict__ evals, const int* __restrict__ gtot,
                               float* __restrict__ out) {
    int wave = (blockIdx.x * blockDim.x + threadIdx.x) >> 6;
    int lane = threadIdx.x & 63;
    if (wave >= gtot[1]) return;
    int node  = __builtin_amdgcn_readfirstlane(slot_node[wave]);
    int start = __builtin_amdgcn_readfirstlane(slot_off[wave]);
    int deg   = __builtin_amdgcn_readfirstlane(cnt[node]);
    int end   = start + deg;

    float r[FT];
    int   c[FT];
#pragma unroll
    for (int t = 0; t < FT; ++t) { r[t] = -INFINITY; c[t] = 0; }

    int i = start;
    for (; i + 3 < end; i += 4) {
        int p0 = sorted[i], p1 = sorted[i + 1], p2 = sorted[i + 2], p3 = sorted[i + 3];
        float v0 = evals[(size_t)(p0 >> 3) * DD + lane];
        float v1 = evals[(size_t)(p1 >> 3) * DD + lane];
        float v2 = evals[(size_t)(p2 >> 3) * DD + lane];
        float v3 = evals[(size_t)(p3 >> 3) * DD + lane];
        int t0 = p0 & 7, t1 = p1 & 7, t2 = p2 & 7, t3 = p3 & 7;
#pragma unroll
        for (int t = 0; t < FT; ++t) {
            bool m0 = (t0 == t); r[t] = m0 ? fmaxf(r[t], v0) : r[t]; c[t] += m0;
            bool m1 = (t1 == t); r[t] = m1 ? fmaxf(r[t], v1) : r[t]; c[t] += m1;
            bool m2 = (t2 == t); r[t] = m2 ? fmaxf(r[t], v2) : r[t]; c[t] += m2;
            bool m3 = (t3 == t); r[t] = m3 ? fmaxf(r[t], v3) : r[t]; c[t] += m3;
        }
    }
    for (; i < end; ++i) {
        int pk = sorted[i];
        int tt = pk & 7;
        float v = evals[(size_t)(pk >> 3) * DD + lane];
#pragma unroll
        for (int t = 0; t < FT; ++t) {
            bool m = (tt == t); r[t] = m ? fmaxf(r[t], v) : r[t]; c[t] += m;
        }
    }

    float res[FT];
#pragma unroll
    for (int f = 0; f < FT; ++f) {
        int matched = c[f];
        float val;
        if (matched == 0)        val = 0.0f;               // no matching edge -> 0
        else if (matched < deg)  val = fmaxf(r[f], 0.0f);  // a masked-to-zero edge exists
        else                     val = r[f];               // all edges matched this type
        res[f] = val;
    }

    // write to every core slot k that maps to this node
    for (int k = head[node]; k >= 0; k = nxt[k]) {
        float* op = out + (size_t)k * (FT * DD) + lane;
#pragma unroll
        for (int f = 0; f < FT; ++f) op[f * DD] = res[f];
    }
}

extern "C" void kernel_launch(void* const* d_in, const int* in_sizes, int n_in,
                              void* d_out, int out_size, void* d_ws, size_t ws_size,
                              hipStream_t stream) {
    const int*   rawd  = (const int*)d_in[0];
    const int*   esrc  = (const int*)d_in[1];
    const int*   edst  = (const int*)d_in[2];
    const float* evals = (const float*)d_in[3];
    const int*   core  = (const int*)d_in[4];
    int nE = in_sizes[1];

    int* wsi       = (int*)d_ws;
    int* cnt       = wsi;
    int* needed    = wsi + 50000;
    int* gtot      = wsi + 100000;
    int* head      = wsi + 100004;
    int* nxt       = wsi + 150004;
    int* slot_node = wsi + 166388;
    int* slot_off  = wsi + 182772;
    int* cursor    = wsi + 199156;
    int* sorted    = wsi + 249156;

    init_kernel<<<(NNODES + 255) / 256, 256, 0, stream>>>(cnt, needed, head, gtot);
    mark_kernel<<<(KK + 255) / 256, 256, 0, stream>>>(core, needed, head, nxt);

    int nE4 = (nE + 3) / 4;
    hist_kernel<<<(nE4 + 255) / 256, 256, 0, stream>>>(
        (const int4*)esrc, needed, cnt, nE);
    alloc_kernel<<<(NNODES + 255) / 256, 256, 0, stream>>>(
        cnt, needed, cursor, slot_node, slot_off, gtot);
    scatter_kernel<<<(nE4 + 255) / 256, 256, 0, stream>>>(
        (const int4*)esrc, (const int4*)edst, rawd, needed, cursor, sorted, nE);

    long long cthreads = (long long)KK * 64;   // upper bound on slots
    compute_kernel<<<(int)((cthreads + 255) / 256), 256, 0, stream>>>(
        slot_node, slot_off, cnt, sorted, head, nxt, evals, gtot, (float*)d_out);
}

// Round 4
// 84.606 us; speedup vs baseline: 25.6076x; 1.4990x over previous
//
#include <hip/hip_runtime.h>

#define NNODES 50000
#define FT 8
#define DD 64
#define KK 16384
#define CAP 128          // per-node edge bucket capacity (mean deg = 32)
#define OVFCAP 32768     // overflow list capacity (never hit in practice)

// ---------------- ws layout (int units) ----------------
// cnt       [0,      50000)    true degree per node (needed nodes only)
// needed    [50000, 100000)
// head      [100000,150000)    node -> first k (linked list), -1 = none
// nxt       [150000,166384)    k -> next k
// slot_node [166384,182768)    compact slot -> node
// gtot      [182768,182772)    [0]=overflow cursor, [1]=slot cursor
// ovf_node  [182772,215540)
// ovf_pk    [215540,248308)
// sorted    [248320,248320+50000*128)  per-node buckets, packed (e<<3)|typ

__global__ void init_kernel(int* __restrict__ cnt, int* __restrict__ needed,
                            int* __restrict__ head, int* __restrict__ gtot) {
    int i = blockIdx.x * 256 + threadIdx.x;
    if (i < NNODES) { cnt[i] = 0; needed[i] = 0; head[i] = -1; }
    if (i < 4) gtot[i] = 0;
}

__global__ void mark_kernel(const int* __restrict__ core, int* __restrict__ needed,
                            int* __restrict__ head, int* __restrict__ nxt,
                            int* __restrict__ slot_node, int* __restrict__ gtot) {
    int k = blockIdx.x * 256 + threadIdx.x;
    if (k >= KK) return;
    int node = core[k];
    nxt[k] = atomicExch(&head[node], k);       // push k onto node's output list
    int old = atomicExch(&needed[node], 1);    // dedup: first toucher owns the slot
    if (!old) {
        int s = atomicAdd(&gtot[1], 1);
        slot_node[s] = node;
    }
}

__global__ void scatter_kernel(const int4* __restrict__ esrc4, const int4* __restrict__ edst4,
                               const int* __restrict__ rawd, const int* __restrict__ needed,
                               int* __restrict__ cnt, int* __restrict__ sorted,
                               int* __restrict__ gtot, int* __restrict__ ovf_node,
                               int* __restrict__ ovf_pk, int nE) {
    int t = blockIdx.x * 256 + threadIdx.x;
    int e = t * 4;
    if (e >= nE) return;
    if (e + 3 < nE) {
        int4 s = esrc4[t];
        int4 d = edst4[t];
        int sv[4] = {s.x, s.y, s.z, s.w};
        int dv[4] = {d.x, d.y, d.z, d.w};
#pragma unroll
        for (int j = 0; j < 4; ++j) {
            int sn = sv[j];
            if (!needed[sn]) continue;
            int pk = ((e + j) << 3) | rawd[dv[j]];
            int p = atomicAdd(&cnt[sn], 1);
            if (p < CAP) {
                sorted[sn * CAP + p] = pk;
            } else {
                int q = atomicAdd(&gtot[0], 1);
                if (q < OVFCAP) { ovf_node[q] = sn; ovf_pk[q] = pk; }
            }
        }
    } else {
        const int* esrc = (const int*)esrc4;
        const int* edst = (const int*)edst4;
        for (; e < nE; ++e) {
            int sn = esrc[e];
            if (!needed[sn]) continue;
            int pk = (e << 3) | rawd[edst[e]];
            int p = atomicAdd(&cnt[sn], 1);
            if (p < CAP) {
                sorted[sn * CAP + p] = pk;
            } else {
                int q = atomicAdd(&gtot[0], 1);
                if (q < OVFCAP) { ovf_node[q] = sn; ovf_pk[q] = pk; }
            }
        }
    }
}

// One wave per compact slot (lane = dim). Register max per type, direct out write.
__global__ void compute_kernel(const int* __restrict__ slot_node, const int* __restrict__ cnt,
                               const int* __restrict__ sorted, const int* __restrict__ head,
                               const int* __restrict__ nxt, const float* __restrict__ evals,
                               const int* __restrict__ gtot, const int* __restrict__ ovf_node,
                               const int* __restrict__ ovf_pk, float* __restrict__ out) {
    int wave = (blockIdx.x * blockDim.x + threadIdx.x) >> 6;
    int lane = threadIdx.x & 63;
    if (wave >= gtot[1]) return;
    int node  = __builtin_amdgcn_readfirstlane(slot_node[wave]);
    int deg   = __builtin_amdgcn_readfirstlane(cnt[node]);
    int stored = deg < CAP ? deg : CAP;
    const int4* bkt4 = (const int4*)(sorted + node * CAP);

    float r[FT];
    int   c[FT];
#pragma unroll
    for (int t = 0; t < FT; ++t) { r[t] = -INFINITY; c[t] = 0; }

    int i = 0;
    for (; i + 3 < stored; i += 4) {
        int4 pk4 = bkt4[i >> 2];
        float v0 = evals[(size_t)(pk4.x >> 3) * DD + lane];
        float v1 = evals[(size_t)(pk4.y >> 3) * DD + lane];
        float v2 = evals[(size_t)(pk4.z >> 3) * DD + lane];
        float v3 = evals[(size_t)(pk4.w >> 3) * DD + lane];
        int t0 = pk4.x & 7, t1 = pk4.y & 7, t2 = pk4.z & 7, t3 = pk4.w & 7;
#pragma unroll
        for (int t = 0; t < FT; ++t) {
            bool m0 = (t0 == t); r[t] = m0 ? fmaxf(r[t], v0) : r[t]; c[t] += m0;
            bool m1 = (t1 == t); r[t] = m1 ? fmaxf(r[t], v1) : r[t]; c[t] += m1;
            bool m2 = (t2 == t); r[t] = m2 ? fmaxf(r[t], v2) : r[t]; c[t] += m2;
            bool m3 = (t3 == t); r[t] = m3 ? fmaxf(r[t], v3) : r[t]; c[t] += m3;
        }
    }
    const int* bkt = sorted + node * CAP;
    for (; i < stored; ++i) {
        int pk = bkt[i];
        int tt = pk & 7;
        float v = evals[(size_t)(pk >> 3) * DD + lane];
#pragma unroll
        for (int t = 0; t < FT; ++t) {
            bool m = (tt == t); r[t] = m ? fmaxf(r[t], v) : r[t]; c[t] += m;
        }
    }
    if (deg > CAP) {   // overflow fallback (unreachable for this dataset, kept for correctness)
        int ovfn = gtot[0]; if (ovfn > OVFCAP) ovfn = OVFCAP;
        for (int j = 0; j < ovfn; ++j) {
            if (ovf_node[j] != node) continue;
            int pk = ovf_pk[j];
            int tt = pk & 7;
            float v = evals[(size_t)(pk >> 3) * DD + lane];
#pragma unroll
            for (int t = 0; t < FT; ++t) {
                bool m = (tt == t); r[t] = m ? fmaxf(r[t], v) : r[t]; c[t] += m;
            }
        }
    }

    float res[FT];
#pragma unroll
    for (int f = 0; f < FT; ++f) {
        int matched = c[f];
        float val;
        if (matched == 0)        val = 0.0f;               // no matching edge -> 0
        else if (matched < deg)  val = fmaxf(r[f], 0.0f);  // a masked-to-zero edge exists
        else                     val = r[f];               // all edges matched this type
        res[f] = val;
    }

    for (int k = head[node]; k >= 0; k = nxt[k]) {
        float* op = out + (size_t)k * (FT * DD) + lane;
#pragma unroll
        for (int f = 0; f < FT; ++f) op[f * DD] = res[f];
    }
}

extern "C" void kernel_launch(void* const* d_in, const int* in_sizes, int n_in,
                              void* d_out, int out_size, void* d_ws, size_t ws_size,
                              hipStream_t stream) {
    const int*   rawd  = (const int*)d_in[0];
    const int*   esrc  = (const int*)d_in[1];
    const int*   edst  = (const int*)d_in[2];
    const float* evals = (const float*)d_in[3];
    const int*   core  = (const int*)d_in[4];
    int nE = in_sizes[1];

    int* wsi       = (int*)d_ws;
    int* cnt       = wsi;
    int* needed    = wsi + 50000;
    int* head      = wsi + 100000;
    int* nxt       = wsi + 150000;
    int* slot_node = wsi + 166384;
    int* gtot      = wsi + 182768;
    int* ovf_node  = wsi + 182772;
    int* ovf_pk    = wsi + 215540;
    int* sorted    = wsi + 248320;   // 16B aligned (248320*4 % 16 == 0)

    init_kernel<<<(NNODES + 255) / 256, 256, 0, stream>>>(cnt, needed, head, gtot);
    mark_kernel<<<(KK + 255) / 256, 256, 0, stream>>>(core, needed, head, nxt, slot_node, gtot);

    int nE4 = (nE + 3) / 4;
    scatter_kernel<<<(nE4 + 255) / 256, 256, 0, stream>>>(
        (const int4*)esrc, (const int4*)edst, rawd, needed, cnt, sorted,
        gtot, ovf_node, ovf_pk, nE);

    long long cthreads = (long long)KK * 64;   // upper bound on slots
    compute_kernel<<<(int)((cthreads + 255) / 256), 256, 0, stream>>>(
        slot_node, cnt, sorted, head, nxt, evals, gtot, ovf_node, ovf_pk, (float*)d_out);
}

// Round 5
// 75.882 us; speedup vs baseline: 28.5515x; 1.1150x over previous
//
#include <hip/hip_runtime.h>

#define NNODES 50000
#define FT 8
#define DD 64
#define KK 16384
#define CAPF 64          // per-(node,type) bucket capacity (mean per-type deg ~4)
#define OVFCAP 32768     // overflow list capacity (never hit for this dataset)
#define NBW 1568         // bitmask words >= ceil(50000/32)

// ---------------- ws layout (int units) ----------------
// cnt       [0,      400000)   per-(node,type) true counts
// bits      [400000, 401568)   needed-node bitmask (6.3 KB, L1-resident)
// head      [401568, 451568)   node -> first k (linked list), -1 = none
// nxt       [451568, 467952)   k -> next k
// slot_node [467952, 484336)   compact slot -> node
// gtot      [484336, 484340)   [0]=overflow cursor, [1]=slot cursor
// ovf_key   [484340, 517108)   overflow (node*8+f)
// ovf_e     [517108, 549876)   overflow edge id
// sorted    [549888, 549888+50000*8*64)  per-(node,type) buckets of edge ids

__global__ void init_kernel(int* __restrict__ cnt, int* __restrict__ bits,
                            int* __restrict__ head, int* __restrict__ gtot) {
    int i = blockIdx.x * 256 + threadIdx.x;
    if (i < NNODES * FT) cnt[i] = 0;
    if (i < NBW) bits[i] = 0;
    if (i < NNODES) head[i] = -1;
    if (i < 4) gtot[i] = 0;
}

__global__ void mark_kernel(const int* __restrict__ core, int* __restrict__ bits,
                            int* __restrict__ head, int* __restrict__ nxt,
                            int* __restrict__ slot_node, int* __restrict__ gtot) {
    int k = blockIdx.x * 256 + threadIdx.x;
    if (k >= KK) return;
    int node = core[k];
    nxt[k] = atomicExch(&head[node], k);                 // push k onto node's list
    unsigned bit = 1u << (node & 31);
    unsigned old = atomicOr((unsigned*)&bits[node >> 5], bit);
    if (!(old & bit)) {                                  // first toucher owns the slot
        int s = atomicAdd(&gtot[1], 1);
        slot_node[s] = node;
    }
}

__global__ void scatter_kernel(const int4* __restrict__ esrc4, const int4* __restrict__ edst4,
                               const int* __restrict__ rawd, const int* __restrict__ bits,
                               int* __restrict__ cnt, int* __restrict__ sorted,
                               int* __restrict__ gtot, int* __restrict__ ovf_key,
                               int* __restrict__ ovf_e, int nE) {
    int t = blockIdx.x * 256 + threadIdx.x;
    int e = t * 4;
    if (e >= nE) return;
    if (e + 3 < nE) {
        int4 s = esrc4[t];
        int4 d = edst4[t];
        int sv[4] = {s.x, s.y, s.z, s.w};
        int dv[4] = {d.x, d.y, d.z, d.w};
#pragma unroll
        for (int j = 0; j < 4; ++j) {
            int sn = sv[j];
            if (!((((unsigned)bits[sn >> 5]) >> (sn & 31)) & 1u)) continue;
            int cell = sn * FT + rawd[dv[j]];
            int p = atomicAdd(&cnt[cell], 1);
            if (p < CAPF) {
                sorted[(size_t)cell * CAPF + p] = e + j;
            } else {
                int q = atomicAdd(&gtot[0], 1);
                if (q < OVFCAP) { ovf_key[q] = cell; ovf_e[q] = e + j; }
            }
        }
    } else {
        const int* esrc = (const int*)esrc4;
        const int* edst = (const int*)edst4;
        for (; e < nE; ++e) {
            int sn = esrc[e];
            if (!((((unsigned)bits[sn >> 5]) >> (sn & 31)) & 1u)) continue;
            int cell = sn * FT + rawd[edst[e]];
            int p = atomicAdd(&cnt[cell], 1);
            if (p < CAPF) {
                sorted[(size_t)cell * CAPF + p] = e;
            } else {
                int q = atomicAdd(&gtot[0], 1);
                if (q < OVFCAP) { ovf_key[q] = cell; ovf_e[q] = e; }
            }
        }
    }
}

// One wave per compact slot (lane = dim). Per-type running max, near-zero VALU.
__global__ void compute_kernel(const int* __restrict__ slot_node, const int* __restrict__ cnt,
                               const int* __restrict__ sorted, const int* __restrict__ head,
                               const int* __restrict__ nxt, const float* __restrict__ evals,
                               const int* __restrict__ gtot, const int* __restrict__ ovf_key,
                               const int* __restrict__ ovf_e, float* __restrict__ out) {
    int wave = (blockIdx.x * blockDim.x + threadIdx.x) >> 6;
    int lane = threadIdx.x & 63;
    if (wave >= gtot[1]) return;
    int node = __builtin_amdgcn_readfirstlane(slot_node[wave]);

    int cf[FT];
    int deg = 0;
    bool anyovf = false;
#pragma unroll
    for (int f = 0; f < FT; ++f) {
        cf[f] = __builtin_amdgcn_readfirstlane(cnt[node * FT + f]);
        deg += cf[f];
        anyovf |= (cf[f] > CAPF);
    }

    float rmax[FT];
#pragma unroll
    for (int f = 0; f < FT; ++f) {
        int n = cf[f] < CAPF ? cf[f] : CAPF;
        const int* bkt = sorted + ((size_t)node * FT + f) * CAPF;
        float m0 = -INFINITY, m1 = -INFINITY, m2 = -INFINITY, m3 = -INFINITY;
        int i = 0;
        for (; i + 3 < n; i += 4) {
            int4 q = *(const int4*)(bkt + i);
            int e0 = __builtin_amdgcn_readfirstlane(q.x);
            int e1 = __builtin_amdgcn_readfirstlane(q.y);
            int e2 = __builtin_amdgcn_readfirstlane(q.z);
            int e3 = __builtin_amdgcn_readfirstlane(q.w);
            m0 = fmaxf(m0, evals[(size_t)e0 * DD + lane]);
            m1 = fmaxf(m1, evals[(size_t)e1 * DD + lane]);
            m2 = fmaxf(m2, evals[(size_t)e2 * DD + lane]);
            m3 = fmaxf(m3, evals[(size_t)e3 * DD + lane]);
        }
        for (; i < n; ++i) {
            int e0 = __builtin_amdgcn_readfirstlane(bkt[i]);
            m0 = fmaxf(m0, evals[(size_t)e0 * DD + lane]);
        }
        rmax[f] = fmaxf(fmaxf(m0, m1), fmaxf(m2, m3));
    }

    if (anyovf) {   // cold path: unreachable for this dataset, kept for correctness
        int no = gtot[0]; if (no > OVFCAP) no = OVFCAP;
        for (int q = 0; q < no; ++q) {
            int key = ovf_key[q];
            if ((key >> 3) != node) continue;
            int f = key & 7;
            float v = evals[(size_t)ovf_e[q] * DD + lane];
#pragma unroll
            for (int t = 0; t < FT; ++t)
                if (t == f) rmax[t] = fmaxf(rmax[t], v);
        }
    }

    float res[FT];
#pragma unroll
    for (int f = 0; f < FT; ++f) {
        int matched = cf[f];
        float val;
        if (matched == 0)        val = 0.0f;                 // no matching edge -> 0
        else if (matched < deg)  val = fmaxf(rmax[f], 0.0f); // a masked-to-zero edge exists
        else                     val = rmax[f];              // all edges matched this type
        res[f] = val;
    }

    for (int k = head[node]; k >= 0; k = nxt[k]) {
        float* op = out + (size_t)k * (FT * DD) + lane;
#pragma unroll
        for (int f = 0; f < FT; ++f) op[f * DD] = res[f];
    }
}

extern "C" void kernel_launch(void* const* d_in, const int* in_sizes, int n_in,
                              void* d_out, int out_size, void* d_ws, size_t ws_size,
                              hipStream_t stream) {
    const int*   rawd  = (const int*)d_in[0];
    const int*   esrc  = (const int*)d_in[1];
    const int*   edst  = (const int*)d_in[2];
    const float* evals = (const float*)d_in[3];
    const int*   core  = (const int*)d_in[4];
    int nE = in_sizes[1];

    int* wsi       = (int*)d_ws;
    int* cnt       = wsi;
    int* bits      = wsi + 400000;
    int* head      = wsi + 401568;
    int* nxt       = wsi + 451568;
    int* slot_node = wsi + 467952;
    int* gtot      = wsi + 484336;
    int* ovf_key   = wsi + 484340;
    int* ovf_e     = wsi + 517108;
    int* sorted    = wsi + 549888;   // byte offset 2199552, 16B aligned

    init_kernel<<<(NNODES * FT + 255) / 256, 256, 0, stream>>>(cnt, bits, head, gtot);
    mark_kernel<<<(KK + 255) / 256, 256, 0, stream>>>(core, bits, head, nxt, slot_node, gtot);

    int nE4 = (nE + 3) / 4;
    scatter_kernel<<<(nE4 + 255) / 256, 256, 0, stream>>>(
        (const int4*)esrc, (const int4*)edst, rawd, bits, cnt, sorted,
        gtot, ovf_key, ovf_e, nE);

    long long cthreads = (long long)KK * 64;   // upper bound on slots
    compute_kernel<<<(int)((cthreads + 255) / 256), 256, 0, stream>>>(
        slot_node, cnt, sorted, head, nxt, evals, gtot, ovf_key, ovf_e, (float*)d_out);
}